// Round 5
// baseline (147.689 us; speedup 1.0000x reference)
//
#include <hip/hip_runtime.h>
#include <hip/hip_bf16.h>

// ---------------------------------------------------------------------------
// CrossAttention: out = softmax((x Wq)(ctx Wk)^T * scale) (ctx Wv) Wo
// B=2, N=M=2048, H=16, D=64, QD=INNER=1024. fp32 in/out, bf16 MFMA inside.
// R5: GEMMs moved to m97 structure (128x128 tile, BK=32, 4x4 frags/wave,
// global_load_lds 16B, 2-barrier loop). Attention unchanged from R4.
// ---------------------------------------------------------------------------

typedef __attribute__((ext_vector_type(8))) __bf16    bf16x8;
typedef __attribute__((ext_vector_type(4))) __bf16    bf16x4;
typedef __attribute__((ext_vector_type(4))) float     f32x4;

#define B_    2
#define H_    16
#define N_    2048
#define M_    2048
#define D_    64
#define QD_   1024

// direct global->LDS async copy, 16B per lane; LDS dest = wave-uniform base + lane*16
__device__ __forceinline__ void gld16(const __bf16* g, __bf16* l) {
    __builtin_amdgcn_global_load_lds(
        (const __attribute__((address_space(1))) unsigned int*)(g),
        (__attribute__((address_space(3))) unsigned int*)(l), 16, 0, 0);
}

// ---------------------------------------------------------------------------
// fused f32->bf16 convert for x (z=0) and context (z=1)
// ---------------------------------------------------------------------------
__global__ __launch_bounds__(256) void cvt2_f32_bf16(const float* __restrict__ x,
                                                     const float* __restrict__ ctx,
                                                     __bf16* __restrict__ xb,
                                                     __bf16* __restrict__ cb) {
    const float* src = blockIdx.y ? ctx : x;
    __bf16*      dst = blockIdx.y ? cb  : xb;
    int i = (blockIdx.x * 256 + threadIdx.x) * 4;
    float4 v = *reinterpret_cast<const float4*>(src + i);
    bf16x4 o;
    o.x = (__bf16)v.x; o.y = (__bf16)v.y; o.z = (__bf16)v.z; o.w = (__bf16)v.w;
    *reinterpret_cast<bf16x4*>(dst + i) = o;
}

// ---------------------------------------------------------------------------
// fused weight transpose+convert: Wt[o][i] = W[i][o], z selects which weight
// ---------------------------------------------------------------------------
__global__ __launch_bounds__(256) void transpose4_cvt(const float* __restrict__ w0,
                                                      const float* __restrict__ w1,
                                                      const float* __restrict__ w2,
                                                      const float* __restrict__ w3,
                                                      __bf16* __restrict__ t0,
                                                      __bf16* __restrict__ t1,
                                                      __bf16* __restrict__ t2,
                                                      __bf16* __restrict__ t3) {
    __shared__ float tile[64][65];
    const int z = blockIdx.z;
    const float* in = (z == 0) ? w0 : (z == 1) ? w1 : (z == 2) ? w2 : w3;
    __bf16*     out = (z == 0) ? t0 : (z == 1) ? t1 : (z == 2) ? t2 : t3;
    const int i0 = blockIdx.x * 64;
    const int o0 = blockIdx.y * 64;
    const int t  = threadIdx.x;
    const int r  = t >> 4;
    const int c4 = (t & 15) * 4;
#pragma unroll
    for (int p = 0; p < 4; ++p) {
        int row = p * 16 + r;
        float4 v = *reinterpret_cast<const float4*>(in + (size_t)(i0 + row) * QD_ + o0 + c4);
        tile[row][c4 + 0] = v.x; tile[row][c4 + 1] = v.y;
        tile[row][c4 + 2] = v.z; tile[row][c4 + 3] = v.w;
    }
    __syncthreads();
#pragma unroll
    for (int p = 0; p < 4; ++p) {
        int orow = p * 16 + r;
        bf16x4 o;
        o.x = (__bf16)tile[c4 + 0][orow];
        o.y = (__bf16)tile[c4 + 1][orow];
        o.z = (__bf16)tile[c4 + 2][orow];
        o.w = (__bf16)tile[c4 + 3][orow];
        *reinterpret_cast<bf16x4*>(out + (size_t)(o0 + orow) * QD_ + i0 + c4) = o;
    }
}

// ---------------------------------------------------------------------------
// GEMM core (m97 structure): 128x128 tile, 4 waves (2x2), wave = 64x64 (4x4
// frags), BK=32, K=1024. global_load_lds 16B staging into LINEAR LDS
// (A[128][32], B[128][32] = 16 KB). 2 barriers per K-step.
// Per K-step per wave: 4 gld16 (stage) + 8 ds_read_b128 + 16 MFMA.
// ---------------------------------------------------------------------------
#define GEMM_BODY(A_, Bt_)                                                                     \
    __shared__ __align__(16) __bf16 Alds[128 * 32];                                            \
    __shared__ __align__(16) __bf16 Blds[128 * 32];                                            \
    const int tid  = threadIdx.x;                                                              \
    const int wid  = tid >> 6;                                                                 \
    const int lane = tid & 63;                                                                 \
    const int l15  = lane & 15;                                                                \
    const int lg   = lane >> 4;                                                                \
    const int wr   = wid >> 1;                                                                 \
    const int wc   = wid & 1;                                                                  \
    const int rowBase = blockIdx.x * 128;                                                      \
    const int colBase = blockIdx.y * 128;                                                      \
    const int srow = wid * 32 + (lane >> 2);                                                   \
    const int skc  = (lane & 3) * 8;                                                           \
    const __bf16* Ag  = A_  + (size_t)(rowBase + srow) * QD_ + skc;                            \
    const __bf16* Ag2 = Ag  + (size_t)16 * QD_;                                                \
    const __bf16* Bg  = Bt_ + (size_t)(colBase + srow) * QD_ + skc;                            \
    const __bf16* Bg2 = Bg  + (size_t)16 * QD_;                                                \
    __bf16* Al  = &Alds[(wid * 32) * 32];                                                      \
    __bf16* Al2 = Al + 16 * 32;                                                                \
    __bf16* Bl  = &Blds[(wid * 32) * 32];                                                      \
    __bf16* Bl2 = Bl + 16 * 32;                                                                \
    f32x4 acc[4][4] = {};                                                                      \
    for (int k0 = 0; k0 < QD_; k0 += 32) {                                                     \
        __syncthreads();                                                                       \
        gld16(Ag + k0, Al);                                                                    \
        gld16(Ag2 + k0, Al2);                                                                  \
        gld16(Bg + k0, Bl);                                                                    \
        gld16(Bg2 + k0, Bl2);                                                                  \
        __syncthreads();                                                                       \
        bf16x8 a[4], b[4];                                                                     \
        _Pragma("unroll")                                                                      \
        for (int m = 0; m < 4; ++m)                                                            \
            a[m] = *reinterpret_cast<const bf16x8*>(&Alds[(wr * 64 + m * 16 + l15) * 32 + lg * 8]); \
        _Pragma("unroll")                                                                      \
        for (int n = 0; n < 4; ++n)                                                            \
            b[n] = *reinterpret_cast<const bf16x8*>(&Blds[(wc * 64 + n * 16 + l15) * 32 + lg * 8]); \
        _Pragma("unroll")                                                                      \
        for (int m = 0; m < 4; ++m)                                                            \
            _Pragma("unroll")                                                                  \
            for (int n = 0; n < 4; ++n)                                                        \
                acc[m][n] = __builtin_amdgcn_mfma_f32_16x16x32_bf16(a[m], b[n], acc[m][n], 0, 0, 0); \
    }

// fused Q/K/V projection: blockIdx.z selects {Q (scaled 0.125), K, V^T} output
__global__ __launch_bounds__(256) void gemm_qkv(const __bf16* __restrict__ xb,
                                                const __bf16* __restrict__ cb,
                                                const __bf16* __restrict__ Wtq,
                                                const __bf16* __restrict__ Wtk,
                                                const __bf16* __restrict__ Wtv,
                                                __bf16* __restrict__ Qb,
                                                __bf16* __restrict__ Kb,
                                                __bf16* __restrict__ Vt) {
    const int z = blockIdx.z;
    const __bf16* Asel = (z == 0) ? xb : cb;
    const __bf16* Bsel = (z == 0) ? Wtq : (z == 1) ? Wtk : Wtv;
    GEMM_BODY(Asel, Bsel)
#pragma unroll
    for (int m = 0; m < 4; ++m)
#pragma unroll
        for (int n = 0; n < 4; ++n)
#pragma unroll
            for (int r = 0; r < 4; ++r) {
                int rr = rowBase + wr * 64 + m * 16 + lg * 4 + r;
                int cc = colBase + wc * 64 + n * 16 + l15;
                float v = acc[m][n][r];
                int b_ = rr >> 11, nn = rr & 2047, hh = cc >> 6, dd = cc & 63;
                if (z == 0) {
                    Qb[((size_t)(b_ * H_ + hh) * N_ + nn) * D_ + dd] = (__bf16)(v * 0.125f);
                } else if (z == 1) {
                    Kb[((size_t)(b_ * H_ + hh) * N_ + nn) * D_ + dd] = (__bf16)v;
                } else {
                    Vt[((size_t)(b_ * H_ + hh) * D_ + dd) * M_ + nn] = (__bf16)v;
                }
            }
}

// final projection: AO @ Wto -> f32 out
__global__ __launch_bounds__(256) void gemm_out(const __bf16* __restrict__ AO,
                                                const __bf16* __restrict__ Wto,
                                                float* __restrict__ out) {
    GEMM_BODY(AO, Wto)
#pragma unroll
    for (int m = 0; m < 4; ++m)
#pragma unroll
        for (int n = 0; n < 4; ++n)
#pragma unroll
            for (int r = 0; r < 4; ++r) {
                int rr = rowBase + wr * 64 + m * 16 + lg * 4 + r;
                int cc = colBase + wc * 64 + n * 16 + l15;
                out[(size_t)rr * QD_ + cc] = acc[m][n][r];
            }
}

// ---------------------------------------------------------------------------
// Attention (R4, unchanged). Grid 512 (XCD-swizzled), 4 waves x 32 q-rows.
// K/V staged in LDS double-buffered, KVBLK=64, XOR-swizzled via pre-swizzled
// global source. Swapped QK^T keeps P lane-local in the PV A-frag layout.
// ---------------------------------------------------------------------------
__global__ __launch_bounds__(256) void attn_kernel(const __bf16* __restrict__ Q,
                                                   const __bf16* __restrict__ K,
                                                   const __bf16* __restrict__ Vt,
                                                   __bf16* __restrict__ AO) {
    __shared__ __align__(16) __bf16 Klds[2][4096];
    __shared__ __align__(16) __bf16 Vlds[2][4096];

    const int logical = (blockIdx.x & 7) * 64 + (blockIdx.x >> 3);
    const int qt   = logical & 15;
    const int bh   = logical >> 4;
    const int b    = bh >> 4;
    const int h    = bh & 15;
    const int wid  = threadIdx.x >> 6;
    const int lane = threadIdx.x & 63;
    const int l15  = lane & 15;
    const int lg   = lane >> 4;
    const int qbase = qt * 128 + wid * 32;

    const __bf16* Qp = Q  + ((size_t)bh * N_ + qbase) * D_;
    const __bf16* Kp = K  + (size_t)bh * M_ * D_;
    const __bf16* Vp = Vt + (size_t)bh * D_ * M_;

    const int srow = (wid << 4) + (lane >> 3);
    const int scol = (lane & 7) << 3;
    const int sk0  = (lane >> 3) & 3;
    const int sk1  = sk0 | 4;
    const int sv   = lane >> 3;
    const int kc0  = scol ^ (sk0 << 3);
    const int kc1  = scol ^ (sk1 << 3);
    const int vc   = scol ^ (sv  << 3);
    __bf16* kl0 = &Klds[0][wid * 1024];
    __bf16* kl1 = &Klds[1][wid * 1024];
    __bf16* vl0 = &Vlds[0][wid * 1024];
    __bf16* vl1 = &Vlds[1][wid * 1024];

#define STAGE(KL, VL, KV0)                                                     \
    gld16(Kp + (size_t)((KV0) + srow)     * D_ + kc0, (KL));                   \
    gld16(Kp + (size_t)((KV0) + srow + 8) * D_ + kc1, (KL) + 512);             \
    gld16(Vp + (size_t)(srow)     * M_ + (KV0) + vc,  (VL));                   \
    gld16(Vp + (size_t)(srow + 8) * M_ + (KV0) + vc,  (VL) + 512);

    const int rm0 = ((l15 >> 2) * 8) + (l15 & 3);
    const int skq = (l15 & 3) | (((l15 >> 2) & 1) << 2);
    const int svq = l15 & 7;
    const int ak00 = rm0 * 64 + (( 0 + lg * 8) ^ (skq << 3));
    const int ak01 = rm0 * 64 + ((32 + lg * 8) ^ (skq << 3));
    const int ak10 = ak00 + 256;
    const int ak11 = ak01 + 256;
    const int av0 = l15 * 64 + (( 0 + lg * 8) ^ (svq << 3));
    const int av1 = l15 * 64 + ((32 + lg * 8) ^ (svq << 3));

    bf16x8 qf00 = *reinterpret_cast<const bf16x8*>(Qp + (size_t)(l15)      * D_ +      lg * 8);
    bf16x8 qf01 = *reinterpret_cast<const bf16x8*>(Qp + (size_t)(l15)      * D_ + 32 + lg * 8);
    bf16x8 qf10 = *reinterpret_cast<const bf16x8*>(Qp + (size_t)(16 + l15) * D_ +      lg * 8);
    bf16x8 qf11 = *reinterpret_cast<const bf16x8*>(Qp + (size_t)(16 + l15) * D_ + 32 + lg * 8);

    f32x4 o00 = {}, o01 = {}, o10 = {}, o11 = {};
    f32x4 o20 = {}, o21 = {}, o30 = {}, o31 = {};
    float rs0 = 0.f, rs1 = 0.f;

#define COMPUTE(KB, VB, KOFF, AV0)                                                              \
    {                                                                                           \
        bf16x8 k00 = *reinterpret_cast<const bf16x8*>((KB) + ak00 + (KOFF));                    \
        bf16x8 k01 = *reinterpret_cast<const bf16x8*>((KB) + ak01 + (KOFF));                    \
        bf16x8 k10 = *reinterpret_cast<const bf16x8*>((KB) + ak10 + (KOFF));                    \
        bf16x8 k11 = *reinterpret_cast<const bf16x8*>((KB) + ak11 + (KOFF));                    \
        bf16x8 v0  = *reinterpret_cast<const bf16x8*>((VB) + (AV0));                            \
        bf16x8 v1  = *reinterpret_cast<const bf16x8*>((VB) + (AV0) + 1024);                     \
        bf16x8 v2  = *reinterpret_cast<const bf16x8*>((VB) + (AV0) + 2048);                     \
        bf16x8 v3  = *reinterpret_cast<const bf16x8*>((VB) + (AV0) + 3072);                     \
        f32x4 s00 = {}, s01 = {}, s10 = {}, s11 = {};                                           \
        s00 = __builtin_amdgcn_mfma_f32_16x16x32_bf16(k00, qf00, s00, 0, 0, 0);                 \
        s00 = __builtin_amdgcn_mfma_f32_16x16x32_bf16(k01, qf01, s00, 0, 0, 0);                 \
        s01 = __builtin_amdgcn_mfma_f32_16x16x32_bf16(k00, qf10, s01, 0, 0, 0);                 \
        s01 = __builtin_amdgcn_mfma_f32_16x16x32_bf16(k01, qf11, s01, 0, 0, 0);                 \
        s10 = __builtin_amdgcn_mfma_f32_16x16x32_bf16(k10, qf00, s10, 0, 0, 0);                 \
        s10 = __builtin_amdgcn_mfma_f32_16x16x32_bf16(k11, qf01, s10, 0, 0, 0);                 \
        s11 = __builtin_amdgcn_mfma_f32_16x16x32_bf16(k10, qf10, s11, 0, 0, 0);                 \
        s11 = __builtin_amdgcn_mfma_f32_16x16x32_bf16(k11, qf11, s11, 0, 0, 0);                 \
        float p00 = __expf(s00[0]), p01 = __expf(s00[1]), p02 = __expf(s00[2]), p03 = __expf(s00[3]); \
        float p04 = __expf(s10[0]), p05 = __expf(s10[1]), p06 = __expf(s10[2]), p07 = __expf(s10[3]); \
        float p10 = __expf(s01[0]), p11 = __expf(s01[1]), p12 = __expf(s01[2]), p13 = __expf(s01[3]); \
        float p14 = __expf(s11[0]), p15 = __expf(s11[1]), p16 = __expf(s11[2]), p17 = __expf(s11[3]); \
        rs0 += (p00 + p01) + (p02 + p03) + (p04 + p05) + (p06 + p07);                           \
        rs1 += (p10 + p11) + (p12 + p13) + (p14 + p15) + (p16 + p17);                           \
        bf16x8 pf0, pf1;                                                                        \
        pf0[0] = (__bf16)p00; pf0[1] = (__bf16)p01; pf0[2] = (__bf16)p02; pf0[3] = (__bf16)p03; \
        pf0[4] = (__bf16)p04; pf0[5] = (__bf16)p05; pf0[6] = (__bf16)p06; pf0[7] = (__bf16)p07; \
        pf1[0] = (__bf16)p10; pf1[1] = (__bf16)p11; pf1[2] = (__bf16)p12; pf1[3] = (__bf16)p13; \
        pf1[4] = (__bf16)p14; pf1[5] = (__bf16)p15; pf1[6] = (__bf16)p16; pf1[7] = (__bf16)p17; \
        o00 = __builtin_amdgcn_mfma_f32_16x16x32_bf16(pf0, v0, o00, 0, 0, 0);                   \
        o01 = __builtin_amdgcn_mfma_f32_16x16x32_bf16(pf1, v0, o01, 0, 0, 0);                   \
        o10 = __builtin_amdgcn_mfma_f32_16x16x32_bf16(pf0, v1, o10, 0, 0, 0);                   \
        o11 = __builtin_amdgcn_mfma_f32_16x16x32_bf16(pf1, v1, o11, 0, 0, 0);                   \
        o20 = __builtin_amdgcn_mfma_f32_16x16x32_bf16(pf0, v2, o20, 0, 0, 0);                   \
        o21 = __builtin_amdgcn_mfma_f32_16x16x32_bf16(pf1, v2, o21, 0, 0, 0);                   \
        o30 = __builtin_amdgcn_mfma_f32_16x16x32_bf16(pf0, v3, o30, 0, 0, 0);                   \
        o31 = __builtin_amdgcn_mfma_f32_16x16x32_bf16(pf1, v3, o31, 0, 0, 0);                   \
    }

    STAGE(kl0, vl0, 0)
    __syncthreads();

    for (int t = 0; t < 32; t += 2) {
        if (t + 1 < 32) { STAGE(kl1, vl1, (t + 1) * 64) }
        COMPUTE(Klds[0], Vlds[0], 0,    av0)
        COMPUTE(Klds[0], Vlds[0], 2048, av1)
        __syncthreads();
        if (t + 2 < 32) { STAGE(kl0, vl0, (t + 2) * 64) }
        COMPUTE(Klds[1], Vlds[1], 0,    av0)
        COMPUTE(Klds[1], Vlds[1], 2048, av1)
        __syncthreads();
    }
#undef STAGE
#undef COMPUTE

    rs0 += __shfl_xor(rs0, 16, 64); rs0 += __shfl_xor(rs0, 32, 64);
    rs1 += __shfl_xor(rs1, 16, 64); rs1 += __shfl_xor(rs1, 32, 64);

#pragma unroll
    for (int r = 0; r < 4; ++r) {
        float i0 = 1.0f / __shfl(rs0, lg * 4 + r, 64);
        float i1 = 1.0f / __shfl(rs1, lg * 4 + r, 64);
        size_t row0 = ((size_t)b * N_ + qbase + lg * 4 + r) * QD_ + h * D_ + l15;
        size_t row1 = ((size_t)b * N_ + qbase + 16 + lg * 4 + r) * QD_ + h * D_ + l15;
        AO[row0 +  0] = (__bf16)(o00[r] * i0);
        AO[row0 + 16] = (__bf16)(o10[r] * i0);
        AO[row0 + 32] = (__bf16)(o20[r] * i0);
        AO[row0 + 48] = (__bf16)(o30[r] * i0);
        AO[row1 +  0] = (__bf16)(o01[r] * i1);
        AO[row1 + 16] = (__bf16)(o11[r] * i1);
        AO[row1 + 32] = (__bf16)(o21[r] * i1);
        AO[row1 + 48] = (__bf16)(o31[r] * i1);
    }
}

// ---------------------------------------------------------------------------
extern "C" void kernel_launch(void* const* d_in, const int* in_sizes, int n_in,
                              void* d_out, int out_size, void* d_ws, size_t ws_size,
                              hipStream_t stream) {
    const float* x   = (const float*)d_in[0];
    const float* ctx = (const float*)d_in[1];
    const float* Wq  = (const float*)d_in[2];
    const float* Wk  = (const float*)d_in[3];
    const float* Wv  = (const float*)d_in[4];
    const float* Wo  = (const float*)d_in[5];

    char* ws = (char*)d_ws;
    __bf16* xb  = (__bf16*)(ws);                      // 0-8 MB
    __bf16* cb  = (__bf16*)(ws + (8u  << 20));        // 8-16 MB
    __bf16* Wtq = (__bf16*)(ws + (16u << 20));        // 16-18 MB
    __bf16* Wtk = (__bf16*)(ws + (18u << 20));        // 18-20
    __bf16* Wtv = (__bf16*)(ws + (20u << 20));        // 20-22
    __bf16* Wto = (__bf16*)(ws + (22u << 20));        // 22-24
    __bf16* Qb  = (__bf16*)(ws + (24u << 20));        // 24-32  [bh][2048][64], pre-scaled 0.125
    __bf16* Kb  = (__bf16*)(ws + (32u << 20));        // 32-40  [bh][2048][64]
    __bf16* Vt  = (__bf16*)(ws + (40u << 20));        // 40-48  [bh][64][2048]
    __bf16* AO  = (__bf16*)(ws + (48u << 20));        // 48-56  [4096][1024]

    cvt2_f32_bf16<<<dim3(4096, 2), 256, 0, stream>>>(x, ctx, xb, cb);
    transpose4_cvt<<<dim3(16, 16, 4), 256, 0, stream>>>(Wq, Wk, Wv, Wo, Wtq, Wtk, Wtv, Wto);
    gemm_qkv<<<dim3(32, 8, 3), 256, 0, stream>>>(xb, cb, Wtq, Wtk, Wtv, Qb, Kb, Vt);
    attn_kernel<<<512, 256, 0, stream>>>(Qb, Kb, Vt, AO);
    gemm_out<<<dim3(32, 8), 256, 0, stream>>>(AO, Wto, (float*)d_out);
}

// Round 6
// 132.391 us; speedup vs baseline: 1.1156x; 1.1156x over previous
//
#include <hip/hip_runtime.h>
#include <hip/hip_bf16.h>

// ---------------------------------------------------------------------------
// CrossAttention: out = softmax((x Wq)(ctx Wk)^T * scale) (ctx Wv) Wo
// B=2, N=M=2048, H=16, D=64, QD=INNER=1024. fp32 in/out, bf16 MFMA inside.
// R6: GEMMs get stage-ahead LDS double-buffering (issue global_load_lds for
// K-step k+1 BEFORE computing step k; ONE barrier per step) — hides the
// load latency that the R5 2-barrier structure exposed every step.
// Attention unchanged from R4.
// ---------------------------------------------------------------------------

typedef __attribute__((ext_vector_type(8))) __bf16    bf16x8;
typedef __attribute__((ext_vector_type(4))) __bf16    bf16x4;
typedef __attribute__((ext_vector_type(4))) float     f32x4;

#define B_    2
#define H_    16
#define N_    2048
#define M_    2048
#define D_    64
#define QD_   1024

// direct global->LDS async copy, 16B per lane; LDS dest = wave-uniform base + lane*16
__device__ __forceinline__ void gld16(const __bf16* g, __bf16* l) {
    __builtin_amdgcn_global_load_lds(
        (const __attribute__((address_space(1))) unsigned int*)(g),
        (__attribute__((address_space(3))) unsigned int*)(l), 16, 0, 0);
}

// ---------------------------------------------------------------------------
// fused f32->bf16 convert for x (z=0) and context (z=1)
// ---------------------------------------------------------------------------
__global__ __launch_bounds__(256) void cvt2_f32_bf16(const float* __restrict__ x,
                                                     const float* __restrict__ ctx,
                                                     __bf16* __restrict__ xb,
                                                     __bf16* __restrict__ cb) {
    const float* src = blockIdx.y ? ctx : x;
    __bf16*      dst = blockIdx.y ? cb  : xb;
    int i = (blockIdx.x * 256 + threadIdx.x) * 4;
    float4 v = *reinterpret_cast<const float4*>(src + i);
    bf16x4 o;
    o.x = (__bf16)v.x; o.y = (__bf16)v.y; o.z = (__bf16)v.z; o.w = (__bf16)v.w;
    *reinterpret_cast<bf16x4*>(dst + i) = o;
}

// ---------------------------------------------------------------------------
// fused weight transpose+convert: Wt[o][i] = W[i][o], z selects which weight
// ---------------------------------------------------------------------------
__global__ __launch_bounds__(256) void transpose4_cvt(const float* __restrict__ w0,
                                                      const float* __restrict__ w1,
                                                      const float* __restrict__ w2,
                                                      const float* __restrict__ w3,
                                                      __bf16* __restrict__ t0,
                                                      __bf16* __restrict__ t1,
                                                      __bf16* __restrict__ t2,
                                                      __bf16* __restrict__ t3) {
    __shared__ float tile[64][65];
    const int z = blockIdx.z;
    const float* in = (z == 0) ? w0 : (z == 1) ? w1 : (z == 2) ? w2 : w3;
    __bf16*     out = (z == 0) ? t0 : (z == 1) ? t1 : (z == 2) ? t2 : t3;
    const int i0 = blockIdx.x * 64;
    const int o0 = blockIdx.y * 64;
    const int t  = threadIdx.x;
    const int r  = t >> 4;
    const int c4 = (t & 15) * 4;
#pragma unroll
    for (int p = 0; p < 4; ++p) {
        int row = p * 16 + r;
        float4 v = *reinterpret_cast<const float4*>(in + (size_t)(i0 + row) * QD_ + o0 + c4);
        tile[row][c4 + 0] = v.x; tile[row][c4 + 1] = v.y;
        tile[row][c4 + 2] = v.z; tile[row][c4 + 3] = v.w;
    }
    __syncthreads();
#pragma unroll
    for (int p = 0; p < 4; ++p) {
        int orow = p * 16 + r;
        bf16x4 o;
        o.x = (__bf16)tile[c4 + 0][orow];
        o.y = (__bf16)tile[c4 + 1][orow];
        o.z = (__bf16)tile[c4 + 2][orow];
        o.w = (__bf16)tile[c4 + 3][orow];
        *reinterpret_cast<bf16x4*>(out + (size_t)(o0 + orow) * QD_ + i0 + c4) = o;
    }
}

// ---------------------------------------------------------------------------
// GEMM core: 128x128 tile, 4 waves (2x2), wave = 64x64 (4x4 frags), BK=32,
// K=1024. Stage-ahead double-buffered LDS: STAGE(k+1) issued before
// COMPUTE(k), ONE barrier per K-step. LDS 2x(128x32 A + 128x32 B) = 32 KB.
// ---------------------------------------------------------------------------
#define GEMM_BODY(A_, Bt_)                                                                     \
    __shared__ __align__(16) __bf16 Alds[2][128 * 32];                                         \
    __shared__ __align__(16) __bf16 Blds[2][128 * 32];                                         \
    const int tid  = threadIdx.x;                                                              \
    const int wid  = tid >> 6;                                                                 \
    const int lane = tid & 63;                                                                 \
    const int l15  = lane & 15;                                                                \
    const int lg   = lane >> 4;                                                                \
    const int wr   = wid >> 1;                                                                 \
    const int wc   = wid & 1;                                                                  \
    const int rowBase = blockIdx.x * 128;                                                      \
    const int colBase = blockIdx.y * 128;                                                      \
    const int srow = wid * 32 + (lane >> 2);                                                   \
    const int skc  = (lane & 3) * 8;                                                           \
    const __bf16* Ag  = A_  + (size_t)(rowBase + srow) * QD_ + skc;                            \
    const __bf16* Ag2 = Ag  + (size_t)16 * QD_;                                                \
    const __bf16* Bg  = Bt_ + (size_t)(colBase + srow) * QD_ + skc;                            \
    const __bf16* Bg2 = Bg  + (size_t)16 * QD_;                                                \
    const int sOff  = (wid * 32) * 32;                                                         \
    const int sOff2 = sOff + 16 * 32;                                                          \
    f32x4 acc[4][4] = {};                                                                      \
    gld16(Ag,  &Alds[0][sOff]);                                                                \
    gld16(Ag2, &Alds[0][sOff2]);                                                               \
    gld16(Bg,  &Blds[0][sOff]);                                                                \
    gld16(Bg2, &Blds[0][sOff2]);                                                               \
    __syncthreads();                                                                           \
    for (int t = 0; t < 32; t += 2) {                                                          \
        if (t + 1 < 32) {                                                                      \
            int kn = (t + 1) * 32;                                                             \
            gld16(Ag + kn,  &Alds[1][sOff]);                                                   \
            gld16(Ag2 + kn, &Alds[1][sOff2]);                                                  \
            gld16(Bg + kn,  &Blds[1][sOff]);                                                   \
            gld16(Bg2 + kn, &Blds[1][sOff2]);                                                  \
        }                                                                                      \
        GCOMPUTE(0)                                                                            \
        __syncthreads();                                                                       \
        if (t + 2 < 32) {                                                                      \
            int kn = (t + 2) * 32;                                                             \
            gld16(Ag + kn,  &Alds[0][sOff]);                                                   \
            gld16(Ag2 + kn, &Alds[0][sOff2]);                                                  \
            gld16(Bg + kn,  &Blds[0][sOff]);                                                   \
            gld16(Bg2 + kn, &Blds[0][sOff2]);                                                  \
        }                                                                                      \
        GCOMPUTE(1)                                                                            \
        __syncthreads();                                                                       \
    }

#define GCOMPUTE(BUF)                                                                          \
    {                                                                                          \
        bf16x8 a[4], b[4];                                                                     \
        _Pragma("unroll")                                                                      \
        for (int m = 0; m < 4; ++m)                                                            \
            a[m] = *reinterpret_cast<const bf16x8*>(&Alds[BUF][(wr * 64 + m * 16 + l15) * 32 + lg * 8]); \
        _Pragma("unroll")                                                                      \
        for (int n = 0; n < 4; ++n)                                                            \
            b[n] = *reinterpret_cast<const bf16x8*>(&Blds[BUF][(wc * 64 + n * 16 + l15) * 32 + lg * 8]); \
        _Pragma("unroll")                                                                      \
        for (int m = 0; m < 4; ++m)                                                            \
            _Pragma("unroll")                                                                  \
            for (int n = 0; n < 4; ++n)                                                        \
                acc[m][n] = __builtin_amdgcn_mfma_f32_16x16x32_bf16(a[m], b[n], acc[m][n], 0, 0, 0); \
    }

// fused Q/K/V projection: blockIdx.z selects {Q (scaled 0.125), K, V^T} output
__global__ __launch_bounds__(256) void gemm_qkv(const __bf16* __restrict__ xb,
                                                const __bf16* __restrict__ cb,
                                                const __bf16* __restrict__ Wtq,
                                                const __bf16* __restrict__ Wtk,
                                                const __bf16* __restrict__ Wtv,
                                                __bf16* __restrict__ Qb,
                                                __bf16* __restrict__ Kb,
                                                __bf16* __restrict__ Vt) {
    const int z = blockIdx.z;
    const __bf16* Asel = (z == 0) ? xb : cb;
    const __bf16* Bsel = (z == 0) ? Wtq : (z == 1) ? Wtk : Wtv;
    GEMM_BODY(Asel, Bsel)
#pragma unroll
    for (int m = 0; m < 4; ++m)
#pragma unroll
        for (int n = 0; n < 4; ++n)
#pragma unroll
            for (int r = 0; r < 4; ++r) {
                int rr = rowBase + wr * 64 + m * 16 + lg * 4 + r;
                int cc = colBase + wc * 64 + n * 16 + l15;
                float v = acc[m][n][r];
                int b_ = rr >> 11, nn = rr & 2047, hh = cc >> 6, dd = cc & 63;
                if (z == 0) {
                    Qb[((size_t)(b_ * H_ + hh) * N_ + nn) * D_ + dd] = (__bf16)(v * 0.125f);
                } else if (z == 1) {
                    Kb[((size_t)(b_ * H_ + hh) * N_ + nn) * D_ + dd] = (__bf16)v;
                } else {
                    Vt[((size_t)(b_ * H_ + hh) * D_ + dd) * M_ + nn] = (__bf16)v;
                }
            }
}

// final projection: AO @ Wto -> f32 out
__global__ __launch_bounds__(256) void gemm_out(const __bf16* __restrict__ AO,
                                                const __bf16* __restrict__ Wto,
                                                float* __restrict__ out) {
    GEMM_BODY(AO, Wto)
#pragma unroll
    for (int m = 0; m < 4; ++m)
#pragma unroll
        for (int n = 0; n < 4; ++n)
#pragma unroll
            for (int r = 0; r < 4; ++r) {
                int rr = rowBase + wr * 64 + m * 16 + lg * 4 + r;
                int cc = colBase + wc * 64 + n * 16 + l15;
                out[(size_t)rr * QD_ + cc] = acc[m][n][r];
            }
}

// ---------------------------------------------------------------------------
// Attention (R4, unchanged). Grid 512 (XCD-swizzled), 4 waves x 32 q-rows.
// K/V staged in LDS double-buffered, KVBLK=64, XOR-swizzled via pre-swizzled
// global source. Swapped QK^T keeps P lane-local in the PV A-frag layout.
// ---------------------------------------------------------------------------
__global__ __launch_bounds__(256) void attn_kernel(const __bf16* __restrict__ Q,
                                                   const __bf16* __restrict__ K,
                                                   const __bf16* __restrict__ Vt,
                                                   __bf16* __restrict__ AO) {
    __shared__ __align__(16) __bf16 Klds[2][4096];
    __shared__ __align__(16) __bf16 Vlds[2][4096];

    const int logical = (blockIdx.x & 7) * 64 + (blockIdx.x >> 3);
    const int qt   = logical & 15;
    const int bh   = logical >> 4;
    const int b    = bh >> 4;
    const int h    = bh & 15;
    const int wid  = threadIdx.x >> 6;
    const int lane = threadIdx.x & 63;
    const int l15  = lane & 15;
    const int lg   = lane >> 4;
    const int qbase = qt * 128 + wid * 32;

    const __bf16* Qp = Q  + ((size_t)bh * N_ + qbase) * D_;
    const __bf16* Kp = K  + (size_t)bh * M_ * D_;
    const __bf16* Vp = Vt + (size_t)bh * D_ * M_;

    const int srow = (wid << 4) + (lane >> 3);
    const int scol = (lane & 7) << 3;
    const int sk0  = (lane >> 3) & 3;
    const int sk1  = sk0 | 4;
    const int sv   = lane >> 3;
    const int kc0  = scol ^ (sk0 << 3);
    const int kc1  = scol ^ (sk1 << 3);
    const int vc   = scol ^ (sv  << 3);
    __bf16* kl0 = &Klds[0][wid * 1024];
    __bf16* kl1 = &Klds[1][wid * 1024];
    __bf16* vl0 = &Vlds[0][wid * 1024];
    __bf16* vl1 = &Vlds[1][wid * 1024];

#define STAGE(KL, VL, KV0)                                                     \
    gld16(Kp + (size_t)((KV0) + srow)     * D_ + kc0, (KL));                   \
    gld16(Kp + (size_t)((KV0) + srow + 8) * D_ + kc1, (KL) + 512);             \
    gld16(Vp + (size_t)(srow)     * M_ + (KV0) + vc,  (VL));                   \
    gld16(Vp + (size_t)(srow + 8) * M_ + (KV0) + vc,  (VL) + 512);

    const int rm0 = ((l15 >> 2) * 8) + (l15 & 3);
    const int skq = (l15 & 3) | (((l15 >> 2) & 1) << 2);
    const int svq = l15 & 7;
    const int ak00 = rm0 * 64 + (( 0 + lg * 8) ^ (skq << 3));
    const int ak01 = rm0 * 64 + ((32 + lg * 8) ^ (skq << 3));
    const int ak10 = ak00 + 256;
    const int ak11 = ak01 + 256;
    const int av0 = l15 * 64 + (( 0 + lg * 8) ^ (svq << 3));
    const int av1 = l15 * 64 + ((32 + lg * 8) ^ (svq << 3));

    bf16x8 qf00 = *reinterpret_cast<const bf16x8*>(Qp + (size_t)(l15)      * D_ +      lg * 8);
    bf16x8 qf01 = *reinterpret_cast<const bf16x8*>(Qp + (size_t)(l15)      * D_ + 32 + lg * 8);
    bf16x8 qf10 = *reinterpret_cast<const bf16x8*>(Qp + (size_t)(16 + l15) * D_ +      lg * 8);
    bf16x8 qf11 = *reinterpret_cast<const bf16x8*>(Qp + (size_t)(16 + l15) * D_ + 32 + lg * 8);

    f32x4 o00 = {}, o01 = {}, o10 = {}, o11 = {};
    f32x4 o20 = {}, o21 = {}, o30 = {}, o31 = {};
    float rs0 = 0.f, rs1 = 0.f;

#define COMPUTE(KB, VB, KOFF, AV0)                                                              \
    {                                                                                           \
        bf16x8 k00 = *reinterpret_cast<const bf16x8*>((KB) + ak00 + (KOFF));                    \
        bf16x8 k01 = *reinterpret_cast<const bf16x8*>((KB) + ak01 + (KOFF));                    \
        bf16x8 k10 = *reinterpret_cast<const bf16x8*>((KB) + ak10 + (KOFF));                    \
        bf16x8 k11 = *reinterpret_cast<const bf16x8*>((KB) + ak11 + (KOFF));                    \
        bf16x8 v0  = *reinterpret_cast<const bf16x8*>((VB) + (AV0));                            \
        bf16x8 v1  = *reinterpret_cast<const bf16x8*>((VB) + (AV0) + 1024);                     \
        bf16x8 v2  = *reinterpret_cast<const bf16x8*>((VB) + (AV0) + 2048);                     \
        bf16x8 v3  = *reinterpret_cast<const bf16x8*>((VB) + (AV0) + 3072);                     \
        f32x4 s00 = {}, s01 = {}, s10 = {}, s11 = {};                                           \
        s00 = __builtin_amdgcn_mfma_f32_16x16x32_bf16(k00, qf00, s00, 0, 0, 0);                 \
        s00 = __builtin_amdgcn_mfma_f32_16x16x32_bf16(k01, qf01, s00, 0, 0, 0);                 \
        s01 = __builtin_amdgcn_mfma_f32_16x16x32_bf16(k00, qf10, s01, 0, 0, 0);                 \
        s01 = __builtin_amdgcn_mfma_f32_16x16x32_bf16(k01, qf11, s01, 0, 0, 0);                 \
        s10 = __builtin_amdgcn_mfma_f32_16x16x32_bf16(k10, qf00, s10, 0, 0, 0);                 \
        s10 = __builtin_amdgcn_mfma_f32_16x16x32_bf16(k11, qf01, s10, 0, 0, 0);                 \
        s11 = __builtin_amdgcn_mfma_f32_16x16x32_bf16(k10, qf10, s11, 0, 0, 0);                 \
        s11 = __builtin_amdgcn_mfma_f32_16x16x32_bf16(k11, qf11, s11, 0, 0, 0);                 \
        float p00 = __expf(s00[0]), p01 = __expf(s00[1]), p02 = __expf(s00[2]), p03 = __expf(s00[3]); \
        float p04 = __expf(s10[0]), p05 = __expf(s10[1]), p06 = __expf(s10[2]), p07 = __expf(s10[3]); \
        float p10 = __expf(s01[0]), p11 = __expf(s01[1]), p12 = __expf(s01[2]), p13 = __expf(s01[3]); \
        float p14 = __expf(s11[0]), p15 = __expf(s11[1]), p16 = __expf(s11[2]), p17 = __expf(s11[3]); \
        rs0 += (p00 + p01) + (p02 + p03) + (p04 + p05) + (p06 + p07);                           \
        rs1 += (p10 + p11) + (p12 + p13) + (p14 + p15) + (p16 + p17);                           \
        bf16x8 pf0, pf1;                                                                        \
        pf0[0] = (__bf16)p00; pf0[1] = (__bf16)p01; pf0[2] = (__bf16)p02; pf0[3] = (__bf16)p03; \
        pf0[4] = (__bf16)p04; pf0[5] = (__bf16)p05; pf0[6] = (__bf16)p06; pf0[7] = (__bf16)p07; \
        pf1[0] = (__bf16)p10; pf1[1] = (__bf16)p11; pf1[2] = (__bf16)p12; pf1[3] = (__bf16)p13; \
        pf1[4] = (__bf16)p14; pf1[5] = (__bf16)p15; pf1[6] = (__bf16)p16; pf1[7] = (__bf16)p17; \
        o00 = __builtin_amdgcn_mfma_f32_16x16x32_bf16(pf0, v0, o00, 0, 0, 0);                   \
        o01 = __builtin_amdgcn_mfma_f32_16x16x32_bf16(pf1, v0, o01, 0, 0, 0);                   \
        o10 = __builtin_amdgcn_mfma_f32_16x16x32_bf16(pf0, v1, o10, 0, 0, 0);                   \
        o11 = __builtin_amdgcn_mfma_f32_16x16x32_bf16(pf1, v1, o11, 0, 0, 0);                   \
        o20 = __builtin_amdgcn_mfma_f32_16x16x32_bf16(pf0, v2, o20, 0, 0, 0);                   \
        o21 = __builtin_amdgcn_mfma_f32_16x16x32_bf16(pf1, v2, o21, 0, 0, 0);                   \
        o30 = __builtin_amdgcn_mfma_f32_16x16x32_bf16(pf0, v3, o30, 0, 0, 0);                   \
        o31 = __builtin_amdgcn_mfma_f32_16x16x32_bf16(pf1, v3, o31, 0, 0, 0);                   \
    }

    STAGE(kl0, vl0, 0)
    __syncthreads();

    for (int t = 0; t < 32; t += 2) {
        if (t + 1 < 32) { STAGE(kl1, vl1, (t + 1) * 64) }
        COMPUTE(Klds[0], Vlds[0], 0,    av0)
        COMPUTE(Klds[0], Vlds[0], 2048, av1)
        __syncthreads();
        if (t + 2 < 32) { STAGE(kl0, vl0, (t + 2) * 64) }
        COMPUTE(Klds[1], Vlds[1], 0,    av0)
        COMPUTE(Klds[1], Vlds[1], 2048, av1)
        __syncthreads();
    }
#undef STAGE
#undef COMPUTE

    rs0 += __shfl_xor(rs0, 16, 64); rs0 += __shfl_xor(rs0, 32, 64);
    rs1 += __shfl_xor(rs1, 16, 64); rs1 += __shfl_xor(rs1, 32, 64);

#pragma unroll
    for (int r = 0; r < 4; ++r) {
        float i0 = 1.0f / __shfl(rs0, lg * 4 + r, 64);
        float i1 = 1.0f / __shfl(rs1, lg * 4 + r, 64);
        size_t row0 = ((size_t)b * N_ + qbase + lg * 4 + r) * QD_ + h * D_ + l15;
        size_t row1 = ((size_t)b * N_ + qbase + 16 + lg * 4 + r) * QD_ + h * D_ + l15;
        AO[row0 +  0] = (__bf16)(o00[r] * i0);
        AO[row0 + 16] = (__bf16)(o10[r] * i0);
        AO[row0 + 32] = (__bf16)(o20[r] * i0);
        AO[row0 + 48] = (__bf16)(o30[r] * i0);
        AO[row1 +  0] = (__bf16)(o01[r] * i1);
        AO[row1 + 16] = (__bf16)(o11[r] * i1);
        AO[row1 + 32] = (__bf16)(o21[r] * i1);
        AO[row1 + 48] = (__bf16)(o31[r] * i1);
    }
}

// ---------------------------------------------------------------------------
extern "C" void kernel_launch(void* const* d_in, const int* in_sizes, int n_in,
                              void* d_out, int out_size, void* d_ws, size_t ws_size,
                              hipStream_t stream) {
    const float* x   = (const float*)d_in[0];
    const float* ctx = (const float*)d_in[1];
    const float* Wq  = (const float*)d_in[2];
    const float* Wk  = (const float*)d_in[3];
    const float* Wv  = (const float*)d_in[4];
    const float* Wo  = (const float*)d_in[5];

    char* ws = (char*)d_ws;
    __bf16* xb  = (__bf16*)(ws);                      // 0-8 MB
    __bf16* cb  = (__bf16*)(ws + (8u  << 20));        // 8-16 MB
    __bf16* Wtq = (__bf16*)(ws + (16u << 20));        // 16-18 MB
    __bf16* Wtk = (__bf16*)(ws + (18u << 20));        // 18-20
    __bf16* Wtv = (__bf16*)(ws + (20u << 20));        // 20-22
    __bf16* Wto = (__bf16*)(ws + (22u << 20));        // 22-24
    __bf16* Qb  = (__bf16*)(ws + (24u << 20));        // 24-32  [bh][2048][64], pre-scaled 0.125
    __bf16* Kb  = (__bf16*)(ws + (32u << 20));        // 32-40  [bh][2048][64]
    __bf16* Vt  = (__bf16*)(ws + (40u << 20));        // 40-48  [bh][64][2048]
    __bf16* AO  = (__bf16*)(ws + (48u << 20));        // 48-56  [4096][1024]

    cvt2_f32_bf16<<<dim3(4096, 2), 256, 0, stream>>>(x, ctx, xb, cb);
    transpose4_cvt<<<dim3(16, 16, 4), 256, 0, stream>>>(Wq, Wk, Wv, Wo, Wtq, Wtk, Wtv, Wto);
    gemm_qkv<<<dim3(32, 8, 3), 256, 0, stream>>>(xb, cb, Wtq, Wtk, Wtv, Qb, Kb, Vt);
    attn_kernel<<<512, 256, 0, stream>>>(Qb, Kb, Vt, AO);
    gemm_out<<<dim3(32, 8), 256, 0, stream>>>(AO, Wto, (float*)d_out);
}

// Round 7
// 123.071 us; speedup vs baseline: 1.2000x; 1.0757x over previous
//
#include <hip/hip_runtime.h>
#include <hip/hip_bf16.h>

// ---------------------------------------------------------------------------
// CrossAttention: out = softmax((x Wq)(ctx Wk)^T * scale) (ctx Wv) Wo
// B=2, N=M=2048, H=16, D=64, QD=INNER=1024. fp32 in/out, bf16 MFMA inside.
// R7: attention VALU diet + TLP: 8 waves x 16 q-rows (16 waves/CU), exp2 via
// prescaled Q (0.125*log2e), row-sums on the MFMA pipe via ones-vector.
// GEMMs unchanged from R6 (stage-ahead dbuf).
// ---------------------------------------------------------------------------

typedef __attribute__((ext_vector_type(8))) __bf16    bf16x8;
typedef __attribute__((ext_vector_type(4))) __bf16    bf16x4;
typedef __attribute__((ext_vector_type(4))) float     f32x4;

#define B_    2
#define H_    16
#define N_    2048
#define M_    2048
#define D_    64
#define QD_   1024

// 0.125 * log2(e): folds both the softmax scale and the exp->exp2 conversion
#define QSCALE 0.18033688011112042f

// direct global->LDS async copy, 16B per lane; LDS dest = wave-uniform base + lane*16
__device__ __forceinline__ void gld16(const __bf16* g, __bf16* l) {
    __builtin_amdgcn_global_load_lds(
        (const __attribute__((address_space(1))) unsigned int*)(g),
        (__attribute__((address_space(3))) unsigned int*)(l), 16, 0, 0);
}

// ---------------------------------------------------------------------------
// fused f32->bf16 convert for x (z=0) and context (z=1)
// ---------------------------------------------------------------------------
__global__ __launch_bounds__(256) void cvt2_f32_bf16(const float* __restrict__ x,
                                                     const float* __restrict__ ctx,
                                                     __bf16* __restrict__ xb,
                                                     __bf16* __restrict__ cb) {
    const float* src = blockIdx.y ? ctx : x;
    __bf16*      dst = blockIdx.y ? cb  : xb;
    int i = (blockIdx.x * 256 + threadIdx.x) * 4;
    float4 v = *reinterpret_cast<const float4*>(src + i);
    bf16x4 o;
    o.x = (__bf16)v.x; o.y = (__bf16)v.y; o.z = (__bf16)v.z; o.w = (__bf16)v.w;
    *reinterpret_cast<bf16x4*>(dst + i) = o;
}

// ---------------------------------------------------------------------------
// fused weight transpose+convert: Wt[o][i] = W[i][o], z selects which weight
// ---------------------------------------------------------------------------
__global__ __launch_bounds__(256) void transpose4_cvt(const float* __restrict__ w0,
                                                      const float* __restrict__ w1,
                                                      const float* __restrict__ w2,
                                                      const float* __restrict__ w3,
                                                      __bf16* __restrict__ t0,
                                                      __bf16* __restrict__ t1,
                                                      __bf16* __restrict__ t2,
                                                      __bf16* __restrict__ t3) {
    __shared__ float tile[64][65];
    const int z = blockIdx.z;
    const float* in = (z == 0) ? w0 : (z == 1) ? w1 : (z == 2) ? w2 : w3;
    __bf16*     out = (z == 0) ? t0 : (z == 1) ? t1 : (z == 2) ? t2 : t3;
    const int i0 = blockIdx.x * 64;
    const int o0 = blockIdx.y * 64;
    const int t  = threadIdx.x;
    const int r  = t >> 4;
    const int c4 = (t & 15) * 4;
#pragma unroll
    for (int p = 0; p < 4; ++p) {
        int row = p * 16 + r;
        float4 v = *reinterpret_cast<const float4*>(in + (size_t)(i0 + row) * QD_ + o0 + c4);
        tile[row][c4 + 0] = v.x; tile[row][c4 + 1] = v.y;
        tile[row][c4 + 2] = v.z; tile[row][c4 + 3] = v.w;
    }
    __syncthreads();
#pragma unroll
    for (int p = 0; p < 4; ++p) {
        int orow = p * 16 + r;
        bf16x4 o;
        o.x = (__bf16)tile[c4 + 0][orow];
        o.y = (__bf16)tile[c4 + 1][orow];
        o.z = (__bf16)tile[c4 + 2][orow];
        o.w = (__bf16)tile[c4 + 3][orow];
        *reinterpret_cast<bf16x4*>(out + (size_t)(o0 + orow) * QD_ + i0 + c4) = o;
    }
}

// ---------------------------------------------------------------------------
// GEMM core: 128x128 tile, 4 waves (2x2), wave = 64x64 (4x4 frags), BK=32,
// K=1024. Stage-ahead double-buffered LDS, ONE barrier per K-step.
// ---------------------------------------------------------------------------
#define GEMM_BODY(A_, Bt_)                                                                     \
    __shared__ __align__(16) __bf16 Alds[2][128 * 32];                                         \
    __shared__ __align__(16) __bf16 Blds[2][128 * 32];                                         \
    const int tid  = threadIdx.x;                                                              \
    const int wid  = tid >> 6;                                                                 \
    const int lane = tid & 63;                                                                 \
    const int l15  = lane & 15;                                                                \
    const int lg   = lane >> 4;                                                                \
    const int wr   = wid >> 1;                                                                 \
    const int wc   = wid & 1;                                                                  \
    const int rowBase = blockIdx.x * 128;                                                      \
    const int colBase = blockIdx.y * 128;                                                      \
    const int srow = wid * 32 + (lane >> 2);                                                   \
    const int skc  = (lane & 3) * 8;                                                           \
    const __bf16* Ag  = A_  + (size_t)(rowBase + srow) * QD_ + skc;                            \
    const __bf16* Ag2 = Ag  + (size_t)16 * QD_;                                                \
    const __bf16* Bg  = Bt_ + (size_t)(colBase + srow) * QD_ + skc;                            \
    const __bf16* Bg2 = Bg  + (size_t)16 * QD_;                                                \
    const int sOff  = (wid * 32) * 32;                                                         \
    const int sOff2 = sOff + 16 * 32;                                                          \
    f32x4 acc[4][4] = {};                                                                      \
    gld16(Ag,  &Alds[0][sOff]);                                                                \
    gld16(Ag2, &Alds[0][sOff2]);                                                               \
    gld16(Bg,  &Blds[0][sOff]);                                                                \
    gld16(Bg2, &Blds[0][sOff2]);                                                               \
    __syncthreads();                                                                           \
    for (int t = 0; t < 32; t += 2) {                                                          \
        if (t + 1 < 32) {                                                                      \
            int kn = (t + 1) * 32;                                                             \
            gld16(Ag + kn,  &Alds[1][sOff]);                                                   \
            gld16(Ag2 + kn, &Alds[1][sOff2]);                                                  \
            gld16(Bg + kn,  &Blds[1][sOff]);                                                   \
            gld16(Bg2 + kn, &Blds[1][sOff2]);                                                  \
        }                                                                                      \
        GCOMPUTE(0)                                                                            \
        __syncthreads();                                                                       \
        if (t + 2 < 32) {                                                                      \
            int kn = (t + 2) * 32;                                                             \
            gld16(Ag + kn,  &Alds[0][sOff]);                                                   \
            gld16(Ag2 + kn, &Alds[0][sOff2]);                                                  \
            gld16(Bg + kn,  &Blds[0][sOff]);                                                   \
            gld16(Bg2 + kn, &Blds[0][sOff2]);                                                  \
        }                                                                                      \
        GCOMPUTE(1)                                                                            \
        __syncthreads();                                                                      \
    }

#define GCOMPUTE(BUF)                                                                          \
    {                                                                                          \
        bf16x8 a[4], b[4];                                                                     \
        _Pragma("unroll")                                                                      \
        for (int m = 0; m < 4; ++m)                                                            \
            a[m] = *reinterpret_cast<const bf16x8*>(&Alds[BUF][(wr * 64 + m * 16 + l15) * 32 + lg * 8]); \
        _Pragma("unroll")                                                                      \
        for (int n = 0; n < 4; ++n)                                                            \
            b[n] = *reinterpret_cast<const bf16x8*>(&Blds[BUF][(wc * 64 + n * 16 + l15) * 32 + lg * 8]); \
        _Pragma("unroll")                                                                      \
        for (int m = 0; m < 4; ++m)                                                            \
            _Pragma("unroll")                                                                  \
            for (int n = 0; n < 4; ++n)                                                        \
                acc[m][n] = __builtin_amdgcn_mfma_f32_16x16x32_bf16(a[m], b[n], acc[m][n], 0, 0, 0); \
    }

// fused Q/K/V projection: blockIdx.z selects {Q (scaled), K, V^T} output
__global__ __launch_bounds__(256) void gemm_qkv(const __bf16* __restrict__ xb,
                                                const __bf16* __restrict__ cb,
                                                const __bf16* __restrict__ Wtq,
                                                const __bf16* __restrict__ Wtk,
                                                const __bf16* __restrict__ Wtv,
                                                __bf16* __restrict__ Qb,
                                                __bf16* __restrict__ Kb,
                                                __bf16* __restrict__ Vt) {
    const int z = blockIdx.z;
    const __bf16* Asel = (z == 0) ? xb : cb;
    const __bf16* Bsel = (z == 0) ? Wtq : (z == 1) ? Wtk : Wtv;
    GEMM_BODY(Asel, Bsel)
#pragma unroll
    for (int m = 0; m < 4; ++m)
#pragma unroll
        for (int n = 0; n < 4; ++n)
#pragma unroll
            for (int r = 0; r < 4; ++r) {
                int rr = rowBase + wr * 64 + m * 16 + lg * 4 + r;
                int cc = colBase + wc * 64 + n * 16 + l15;
                float v = acc[m][n][r];
                int b_ = rr >> 11, nn = rr & 2047, hh = cc >> 6, dd = cc & 63;
                if (z == 0) {
                    Qb[((size_t)(b_ * H_ + hh) * N_ + nn) * D_ + dd] = (__bf16)(v * QSCALE);
                } else if (z == 1) {
                    Kb[((size_t)(b_ * H_ + hh) * N_ + nn) * D_ + dd] = (__bf16)v;
                } else {
                    Vt[((size_t)(b_ * H_ + hh) * D_ + dd) * M_ + nn] = (__bf16)v;
                }
            }
}

// final projection: AO @ Wto -> f32 out
__global__ __launch_bounds__(256) void gemm_out(const __bf16* __restrict__ AO,
                                                const __bf16* __restrict__ Wto,
                                                float* __restrict__ out) {
    GEMM_BODY(AO, Wto)
#pragma unroll
    for (int m = 0; m < 4; ++m)
#pragma unroll
        for (int n = 0; n < 4; ++n)
#pragma unroll
            for (int r = 0; r < 4; ++r) {
                int rr = rowBase + wr * 64 + m * 16 + lg * 4 + r;
                int cc = colBase + wc * 64 + n * 16 + l15;
                out[(size_t)rr * QD_ + cc] = acc[m][n][r];
            }
}

// ---------------------------------------------------------------------------
// Attention R7. Grid 512 (XCD-swizzled), 8 waves x 16 q-rows (512 threads),
// 16 waves/CU. K/V LDS double-buffered (32 KB), KVBLK=64; each wave stages its
// own 8-row K and V slices (2 gld16/step). XOR swizzle via pre-swizzled global
// source. Swapped QK^T -> P lane-local; P row-sums via ones-MFMA (o_rs).
// Q pre-scaled by 0.125*log2e -> P = exp2(S) on the native v_exp_f32.
// ---------------------------------------------------------------------------
__global__ __launch_bounds__(512, 4) void attn_kernel(const __bf16* __restrict__ Q,
                                                      const __bf16* __restrict__ K,
                                                      const __bf16* __restrict__ Vt,
                                                      __bf16* __restrict__ AO) {
    __shared__ __align__(16) __bf16 Klds[2][4096];
    __shared__ __align__(16) __bf16 Vlds[2][4096];

    const int logical = (blockIdx.x & 7) * 64 + (blockIdx.x >> 3);
    const int qt   = logical & 15;
    const int bh   = logical >> 4;
    const int b    = bh >> 4;
    const int h    = bh & 15;
    const int wid  = threadIdx.x >> 6;     // 0..7
    const int lane = threadIdx.x & 63;
    const int l15  = lane & 15;
    const int lg   = lane >> 4;
    const int qbase = qt * 128 + wid * 16;

    const __bf16* Qp = Q  + ((size_t)bh * N_ + qbase) * D_;
    const __bf16* Kp = K  + (size_t)bh * M_ * D_;
    const __bf16* Vp = Vt + (size_t)bh * D_ * M_;

    // ---- staging: wave w covers rows w*8+rg (rg=lane>>3) of K (kv) and V (d)
    const int rg   = lane >> 3;
    const int ch   = lane & 7;
    const int skw  = (rg & 3) | ((wid & 1) << 2);   // sK(w*8+rg)
    const int kc   = (ch ^ skw) << 3;               // pre-swizzled K source col
    const int vc   = (ch ^ rg) << 3;                // sV(w*8+rg) = rg
    const int srow = wid * 8 + rg;
    const int ldst = wid * 512;                     // LDS elem base for this wave

#define STAGE(BUF, KV0)                                                        \
    gld16(Kp + (size_t)((KV0) + srow) * D_ + kc, &Klds[BUF][ldst]);            \
    gld16(Vp + (size_t)srow * M_ + (KV0) + vc,  &Vlds[BUF][ldst]);

    // ---- read geometry (identical to R4 tile layout) ----
    const int rm0 = ((l15 >> 2) * 8) + (l15 & 3);   // permuted K row (QK^T swap)
    const int sq  = (l15 & 7) << 3;                 // sK(rm0)=sV(row)= l15&7
    const int ak00 = rm0 * 64 + (( 0 + lg * 8) ^ sq);
    const int ak01 = rm0 * 64 + ((32 + lg * 8) ^ sq);
    const int ak10 = ak00 + 256;                    // +4 kv rows
    const int ak11 = ak01 + 256;
    const int av0 = l15 * 64 + (( 0 + lg * 8) ^ sq);
    const int av1 = l15 * 64 + ((32 + lg * 8) ^ sq);

    // Q fragments (B-operand), 16 q-rows
    bf16x8 qf0 = *reinterpret_cast<const bf16x8*>(Qp + (size_t)l15 * D_ +      lg * 8);
    bf16x8 qf1 = *reinterpret_cast<const bf16x8*>(Qp + (size_t)l15 * D_ + 32 + lg * 8);

    bf16x8 onesf;
#pragma unroll
    for (int j = 0; j < 8; ++j) onesf[j] = (__bf16)1.0f;

    f32x4 o0 = {}, o1 = {}, o2 = {}, o3 = {}, ors = {};

#define COMPUTE(KB, VB, KOFF, AV)                                                               \
    {                                                                                           \
        bf16x8 k00 = *reinterpret_cast<const bf16x8*>((KB) + ak00 + (KOFF));                    \
        bf16x8 k01 = *reinterpret_cast<const bf16x8*>((KB) + ak01 + (KOFF));                    \
        bf16x8 k10 = *reinterpret_cast<const bf16x8*>((KB) + ak10 + (KOFF));                    \
        bf16x8 k11 = *reinterpret_cast<const bf16x8*>((KB) + ak11 + (KOFF));                    \
        bf16x8 v0  = *reinterpret_cast<const bf16x8*>((VB) + (AV));                             \
        bf16x8 v1  = *reinterpret_cast<const bf16x8*>((VB) + (AV) + 1024);                      \
        bf16x8 v2  = *reinterpret_cast<const bf16x8*>((VB) + (AV) + 2048);                      \
        bf16x8 v3  = *reinterpret_cast<const bf16x8*>((VB) + (AV) + 3072);                      \
        f32x4 s0 = {}, s1 = {};                                                                 \
        s0 = __builtin_amdgcn_mfma_f32_16x16x32_bf16(k00, qf0, s0, 0, 0, 0);                    \
        s0 = __builtin_amdgcn_mfma_f32_16x16x32_bf16(k01, qf1, s0, 0, 0, 0);                    \
        s1 = __builtin_amdgcn_mfma_f32_16x16x32_bf16(k10, qf0, s1, 0, 0, 0);                    \
        s1 = __builtin_amdgcn_mfma_f32_16x16x32_bf16(k11, qf1, s1, 0, 0, 0);                    \
        bf16x8 pf;                                                                              \
        pf[0] = (__bf16)__builtin_amdgcn_exp2f(s0[0]);                                          \
        pf[1] = (__bf16)__builtin_amdgcn_exp2f(s0[1]);                                          \
        pf[2] = (__bf16)__builtin_amdgcn_exp2f(s0[2]);                                          \
        pf[3] = (__bf16)__builtin_amdgcn_exp2f(s0[3]);                                          \
        pf[4] = (__bf16)__builtin_amdgcn_exp2f(s1[0]);                                          \
        pf[5] = (__bf16)__builtin_amdgcn_exp2f(s1[1]);                                          \
        pf[6] = (__bf16)__builtin_amdgcn_exp2f(s1[2]);                                          \
        pf[7] = (__bf16)__builtin_amdgcn_exp2f(s1[3]);                                          \
        ors = __builtin_amdgcn_mfma_f32_16x16x32_bf16(pf, onesf, ors, 0, 0, 0);                 \
        o0 = __builtin_amdgcn_mfma_f32_16x16x32_bf16(pf, v0, o0, 0, 0, 0);                      \
        o1 = __builtin_amdgcn_mfma_f32_16x16x32_bf16(pf, v1, o1, 0, 0, 0);                      \
        o2 = __builtin_amdgcn_mfma_f32_16x16x32_bf16(pf, v2, o2, 0, 0, 0);                      \
        o3 = __builtin_amdgcn_mfma_f32_16x16x32_bf16(pf, v3, o3, 0, 0, 0);                      \
    }

    STAGE(0, 0)
    __syncthreads();

    for (int t = 0; t < 32; t += 2) {
        if (t + 1 < 32) { STAGE(1, (t + 1) * 64) }
        COMPUTE(Klds[0], Vlds[0], 0,    av0)
        COMPUTE(Klds[0], Vlds[0], 2048, av1)
        __syncthreads();
        if (t + 2 < 32) { STAGE(0, (t + 2) * 64) }
        COMPUTE(Klds[1], Vlds[1], 0,    av0)
        COMPUTE(Klds[1], Vlds[1], 2048, av1)
        __syncthreads();
    }
#undef STAGE
#undef COMPUTE

    // lane holds O[q=qbase+lg*4+r][d=n*16+l15] in o_n[r]; row sum in ors[r].
#pragma unroll
    for (int r = 0; r < 4; ++r) {
        float inv = 1.0f / ors[r];
        size_t row = ((size_t)b * N_ + qbase + lg * 4 + r) * QD_ + h * D_ + l15;
        AO[row +  0] = (__bf16)(o0[r] * inv);
        AO[row + 16] = (__bf16)(o1[r] * inv);
        AO[row + 32] = (__bf16)(o2[r] * inv);
        AO[row + 48] = (__bf16)(o3[r] * inv);
    }
}

// ---------------------------------------------------------------------------
extern "C" void kernel_launch(void* const* d_in, const int* in_sizes, int n_in,
                              void* d_out, int out_size, void* d_ws, size_t ws_size,
                              hipStream_t stream) {
    const float* x   = (const float*)d_in[0];
    const float* ctx = (const float*)d_in[1];
    const float* Wq  = (const float*)d_in[2];
    const float* Wk  = (const float*)d_in[3];
    const float* Wv  = (const float*)d_in[4];
    const float* Wo  = (const float*)d_in[5];

    char* ws = (char*)d_ws;
    __bf16* xb  = (__bf16*)(ws);                      // 0-8 MB
    __bf16* cb  = (__bf16*)(ws + (8u  << 20));        // 8-16 MB
    __bf16* Wtq = (__bf16*)(ws + (16u << 20));        // 16-18 MB
    __bf16* Wtk = (__bf16*)(ws + (18u << 20));        // 18-20
    __bf16* Wtv = (__bf16*)(ws + (20u << 20));        // 20-22
    __bf16* Wto = (__bf16*)(ws + (22u << 20));        // 22-24
    __bf16* Qb  = (__bf16*)(ws + (24u << 20));        // 24-32  [bh][2048][64], pre-scaled
    __bf16* Kb  = (__bf16*)(ws + (32u << 20));        // 32-40  [bh][2048][64]
    __bf16* Vt  = (__bf16*)(ws + (40u << 20));        // 40-48  [bh][64][2048]
    __bf16* AO  = (__bf16*)(ws + (48u << 20));        // 48-56  [4096][1024]

    cvt2_f32_bf16<<<dim3(4096, 2), 256, 0, stream>>>(x, ctx, xb, cb);
    transpose4_cvt<<<dim3(16, 16, 4), 256, 0, stream>>>(Wq, Wk, Wv, Wo, Wtq, Wtk, Wtv, Wto);
    gemm_qkv<<<dim3(32, 8, 3), 256, 0, stream>>>(xb, cb, Wtq, Wtk, Wtv, Qb, Kb, Vt);
    attn_kernel<<<512, 512, 0, stream>>>(Qb, Kb, Vt, AO);
    gemm_out<<<dim3(32, 8), 256, 0, stream>>>(AO, Wto, (float*)d_out);
}